// Round 5
// baseline (223.809 us; speedup 1.0000x reference)
//
#include <hip/hip_runtime.h>
#include <hip/hip_cooperative_groups.h>
#include <hip/hip_bf16.h>
#include <math.h>

namespace cg = cooperative_groups;

// Sizes fixed by the reference setup: B=512, F=512, max_depth=8 -> S=255 splits, N=511 nodes, NC=21.
#define BATCH 512
#define FDIM  512
#define NSPL  255
#define NNOD  511
#define NC    21

// NOTE (prior-session post-mortems): the scan's merge dynamics depend on EXACT
// bit-level ties. Changes that broke them (full 512-iter blowup, ~900 us):
//   (1) duplicating f64 blend expressions (ffp-contract divergence);
//   (2) replacing __shfl_xor butterflies with DPP/swizzle equivalents.
// k_scan below is byte-identical to the validated round-2/4 version.
//
// ACCOUNTING MODEL (solved via rounds 2/3/4): per-launch overhead ~10.5 us;
// scan ~36 us; real kernels ~8 us. Launch count is the lever.
// ROUND-3 POST-MORTEM: intra-grid ticket+__threadfence producer/consumer is
// CATASTROPHIC on gfx950 (cross-XCD coherence serialization). Launch
// boundaries or cooperative grid.sync are the only coherence points.
// ROUND-4 POST-MORTEM: single full-K GEMM with 1 wave/SIMD exposed LDS
// latency (~31 us). Reverted to the validated split-K shape.
// ROUND-5 CHANGE: cooperative k_front = {split-K gemm (verbatim, n=8,
// identical block mapping), grid.sync, k_qreduce (verbatim mapping),
// grid.sync, k_ga (verbatim)}. All phase bodies are the validated ones =>
// identical bits. Occupancy + launch-error guards fall back to the
// validated 5-launch path.

// ---------------------------------------------------------------------------
// Phase bodies (verbatim validated arithmetic), shared by standalone kernels
// and the cooperative front kernel.
// ---------------------------------------------------------------------------
__device__ __forceinline__ void gemm_body(const float* __restrict__ x,
                                          const float* __restrict__ W,
                                          float* __restrict__ partial,
                                          int fpc, int bx, int byy, int bz, int tid) {
  __shared__ float Ws[64 * 68];
  __shared__ float xT[64 * 68];
  const int s0 = bx * 64;
  const int b0 = byy * 64;
  const int f0 = bz * fpc;
  const int sx = tid & 15;
  const int by = tid >> 4;
  float acc[4][4];
#pragma unroll
  for (int i = 0; i < 4; ++i)
#pragma unroll
    for (int j = 0; j < 4; ++j) acc[i][j] = 0.f;

  for (int fc = f0; fc < f0 + fpc; fc += 64) {
    {
      int si = tid & 63, fr = tid >> 6;
#pragma unroll
      for (int r = 0; r < 16; ++r) {
        int fi = fr + r * 4;
        int s = s0 + si;
        Ws[fi * 68 + si] = (s < NSPL) ? W[(fc + fi) * NSPL + s] : 0.f;
      }
      int j = tid & 63, ir = tid >> 6;
#pragma unroll
      for (int r = 0; r < 16; ++r) {
        int i = ir + r * 4;
        xT[j * 68 + i] = x[(b0 + i) * FDIM + (fc + j)];
      }
    }
    __syncthreads();
#pragma unroll 8
    for (int f = 0; f < 64; ++f) {
      float4 av = *(const float4*)&Ws[f * 68 + sx * 4];
      float4 xv = *(const float4*)&xT[f * 68 + by * 4];
      const float a4[4] = {av.x, av.y, av.z, av.w};
      const float x4[4] = {xv.x, xv.y, xv.z, xv.w};
#pragma unroll
      for (int i = 0; i < 4; ++i)
#pragma unroll
        for (int j = 0; j < 4; ++j) acc[i][j] += a4[i] * x4[j];
    }
    __syncthreads();
  }

  float* pout = partial + (size_t)bz * (256 * BATCH);
#pragma unroll
  for (int i = 0; i < 4; ++i) {
    int s = s0 + sx * 4 + i;
    if (s < NSPL) {
      float4 v = make_float4(acc[i][0], acc[i][1], acc[i][2], acc[i][3]);
      *(float4*)&pout[s * BATCH + b0 + by * 4] = v;
    }
  }
}

__device__ __forceinline__ void reduce_body(const float* __restrict__ partial,
                                            const float* __restrict__ bias,
                                            float* __restrict__ qsT, int n,
                                            int bid, int tid) {
  int idx = bid * 256 + tid;
  if (idx < NSPL * BATCH) {
    int s = idx >> 9;
    float v = 0.f;
    for (int c = 0; c < n; ++c) v += partial[(size_t)c * (256 * BATCH) + idx];
    qsT[idx] = v + bias[s];
  }
}

// q_node walk (validated — same fminf chain as the original reference path)
__device__ __forceinline__ float qnode_walk(const float* __restrict__ qsT, int n, int b) {
  float q = 1.0f;
  int a = n;
  while (a > 0) {
    int p = (a - 1) >> 1;
    float v = qsT[p * BATCH + b];
    q = fminf(q, (a & 1) ? -v : v);
    a = p;
  }
  return q;
}

// g_a row for node n (byte-identical arithmetic to validated k_ga) + agrp0[n]
// + qnodeT[n][b] (free coalesced store consumed by k_clip).
__device__ __forceinline__ void ga_body(const float* __restrict__ qsT,
                                        float* __restrict__ ga,
                                        double* __restrict__ agrp0,
                                        float* __restrict__ qnodeT,
                                        int n, int tid) {
  __shared__ float qs[BATCH];
  __shared__ double part[4][NC];
  __shared__ float gaRow[NC];
  __shared__ double zS[NC];
  __shared__ double eS[NC];
  __shared__ double mS;
#pragma unroll
  for (int rep = 0; rep < 2; ++rep) {
    int b = tid + rep * 256;
    float q = qnode_walk(qsT, n, b);
    qs[b] = q;
    qnodeT[n * BATCH + b] = q;
  }
  __syncthreads();
  if (tid < 4 * NC) {
    int c = tid % NC, chunk = tid / NC;
    double ac = 0.05 * (double)c;
    double ssum = 0.0;
    int b0 = chunk * 128;
    for (int b = b0; b < b0 + 128; ++b) {
      float qh = qs[b] + 0.5f;          // f32 add (NumPy scalar promotion keeps f32)
      double dqh = (double)qh;
      if (ac <= dqh) { double d = ac - dqh; ssum += d * d; }
    }
    part[chunk][c] = ssum;
  }
  __syncthreads();
  if (tid < NC) {
    double ac = 0.05 * (double)tid;
    double ssum = ((part[0][tid] + part[1][tid]) + part[2][tid]) + part[3][tid];
    float gv = (float)(0.5 * ac * ac + 0.5 * ssum);
    ga[n * NC + tid] = gv;
    gaRow[tid] = gv;    // same f32 bits the serial softmin consumed
  }
  __syncthreads();

  // softmin: exps parallel across 21 lanes (deterministic => same bits);
  // order-sensitive chains (m, S, A) verbatim serial on tid 0
  if (tid < NC) zS[tid] = -100.0 * (double)gaRow[tid];
  __syncthreads();
  if (tid == 0) {
    double m = -1e300;
#pragma unroll
    for (int c = 0; c < NC; ++c) m = fmax(m, zS[c]);
    mS = m;
  }
  __syncthreads();
  if (tid < NC) eS[tid] = exp(zS[tid] - mS);
  __syncthreads();
  if (tid == 0) {
    double S = 0.0;
#pragma unroll
    for (int c = 0; c < NC; ++c) S += eS[c];
    double A = 0.0;
#pragma unroll
    for (int c = 0; c < NC; ++c) A += (0.05 * (double)c) * (eS[c] / S);
    agrp0[n] = A;
  }
}

// ---------------------------------------------------------------------------
// Standalone kernels (validated fallback path)
// ---------------------------------------------------------------------------
__global__ __launch_bounds__(256) void k_qgemm(const float* __restrict__ x,
                                               const float* __restrict__ W,
                                               float* __restrict__ partial,
                                               int fpc) {
  gemm_body(x, W, partial, fpc, blockIdx.x, blockIdx.y, blockIdx.z, threadIdx.x);
}

__global__ __launch_bounds__(256) void k_qreduce(const float* __restrict__ partial,
                                                 const float* __restrict__ bias,
                                                 float* __restrict__ qsT, int n) {
  reduce_body(partial, bias, qsT, n, blockIdx.x, threadIdx.x);
}

__global__ __launch_bounds__(256) void k_ga(const float* __restrict__ qsT,
                                            float* __restrict__ ga,
                                            double* __restrict__ agrp0,
                                            float* __restrict__ qnodeT) {
  ga_body(qsT, ga, agrp0, qnodeT, blockIdx.x, threadIdx.x);
}

// Fallback GEMM (used only if workspace too small for split-K).
__global__ __launch_bounds__(256) void k_qsplitT_fb(const float* __restrict__ x,
                                                    const float* __restrict__ W,
                                                    const float* __restrict__ bias,
                                                    float* __restrict__ qsT) {
  const int s = threadIdx.x;
  const int b0 = blockIdx.x * 8;
  if (s >= NSPL) return;
  float acc0[8], acc1[8];
#pragma unroll
  for (int i = 0; i < 8; ++i) { acc0[i] = 0.f; acc1[i] = 0.f; }
#pragma unroll 2
  for (int f = 0; f < 256; ++f) {
    float w0 = W[f * NSPL + s];
    float w1 = W[(f + 256) * NSPL + s];
#pragma unroll
    for (int i = 0; i < 8; ++i) {
      acc0[i] += x[(b0 + i) * FDIM + f] * w0;
      acc1[i] += x[(b0 + i) * FDIM + f + 256] * w1;
    }
  }
  float bs = bias[s];
#pragma unroll
  for (int i = 0; i < 8; ++i) qsT[s * BATCH + b0 + i] = (acc0[i] + acc1[i]) + bs;
}

// ---------------------------------------------------------------------------
// Cooperative front kernel: gemm (256 blocks' worth) | sync | reduce | sync | ga.
// Phase bodies verbatim => qsT/ga/agrp0/qnodeT bits identical to fallback.
// n (split-K chunks) hardcoded 8; host only uses this path when n==8.
// ---------------------------------------------------------------------------
__global__ __launch_bounds__(256) void k_front(const float* __restrict__ x,
                                               const float* __restrict__ W,
                                               const float* __restrict__ bias,
                                               float* __restrict__ partial,
                                               float* __restrict__ qsT,
                                               float* __restrict__ ga,
                                               double* __restrict__ agrp0,
                                               float* __restrict__ qnodeT) {
  const int tid = threadIdx.x;
  const int bid = blockIdx.x;
  cg::grid_group grid = cg::this_grid();

  if (bid < 256)
    gemm_body(x, W, partial, 64, bid & 3, (bid >> 2) & 7, bid >> 5, tid);
  grid.sync();
  if (bid < 510)
    reduce_body(partial, bias, qsT, 8, bid, tid);
  grid.sync();
  ga_body(qsT, ga, agrp0, qnodeT, bid, tid);
}

// ---------------------------------------------------------------------------
// Kernel 3: the sequential scan — BYTE-IDENTICAL to the validated round-2/4
// version. anode array is load-bearing (exact-tie mechanism); __shfl_xor
// butterflies are load-bearing (see note at top). Do not touch.
// ---------------------------------------------------------------------------
__global__ __launch_bounds__(64) void k_scan(const float* __restrict__ ga_g,
                                             const double* __restrict__ agrp0,
                                             double* __restrict__ a_node_out) {
  __shared__ float gaS[NNOD * NC];        // 42924 B
  __shared__ double agrp[512];            // 4096 B
  __shared__ double anode[512];           // 4096 B
  __shared__ float kfS[512];              // 2048 B
  const int lane = threadIdx.x;

  {
    const float4* src = (const float4*)ga_g;
    float4* dst = (float4*)gaS;
    const int n4 = (NNOD * NC) / 4;       // 2682
#pragma unroll 4
    for (int i = lane; i < n4; i += 64) dst[i] = src[i];
    if (lane < (NNOD * NC) - n4 * 4) gaS[n4 * 4 + lane] = ga_g[n4 * 4 + lane];
  }
  for (int i = lane; i < 512; i += 64) {
    agrp[i] = (i < NNOD) ? agrp0[i] : 0.0;
    anode[i] = 0.0;
    kfS[i] = 0.0f;
  }
  __syncthreads();

  int t = 0, p = 0;
  double areg[8];
  int iter = 0;
  for (;;) {
    if (iter > 0) {
      // phase Z: recompute a_grp for groups t (lanes 0..31) and p (lanes 32..63)
      int j = lane >> 5, c = lane & 31;
      int g = j ? p : t;
      double z = -1e300;
      if (c < NC) {
        double acc = (1.0 - (double)kfS[g]) * (double)gaS[g * NC + c];
        int l = 2 * g + 1, r = 2 * g + 2;
        if (l < NNOD) acc = acc + (double)kfS[l] * (double)gaS[l * NC + c];
        if (r < NNOD) acc = acc + (double)kfS[r] * (double)gaS[r * NC + c];
        z = -100.0 * acc;
      }
      double m = z;
#pragma unroll
      for (int off = 16; off >= 1; off >>= 1) m = fmax(m, __shfl_xor(m, off, 32));
      double e = (c < NC) ? exp(z - m) : 0.0;
      double S = e;
#pragma unroll
      for (int off = 16; off >= 1; off >>= 1) S += __shfl_xor(S, off, 32);
      double term = (c < NC) ? (0.05 * (double)c) * (e / S) : 0.0;
#pragma unroll
      for (int off = 16; off >= 1; off >>= 1) term += __shfl_xor(term, off, 32);
      if (c == 0) agrp[g] = term;
      __syncthreads();
    }

    // phase N: a_node[n] = k_n*a_grp[par] + (1-k_n)*a_grp[n]
#pragma unroll
    for (int u = 0; u < 8; ++u) {
      int n = lane + (u << 6);
      if (n < NNOD) {
        double kn = (double)kfS[n];
        double agn = agrp[n];
        double an;
        if (n == 0) an = agn;
        else an = kn * agrp[(n - 1) >> 1] + (1.0 - kn) * agn;
        areg[u] = an;
        anode[n] = an;
      }
    }
    __syncthreads();

    // phase V: viol + argmax (first-index tie-break)
    double bv = -1e300; int bi = 0x7fffffff;
#pragma unroll
    for (int u = 0; u < 8; ++u) {
      int n = lane + (u << 6);
      if (n < NNOD) {
        double ap = (n == 0) ? 1.0 : anode[(n - 1) >> 1];
        double vi = areg[u] - ap;
        if (vi > bv) { bv = vi; bi = n; }
      }
    }
#pragma unroll
    for (int off = 32; off >= 1; off >>= 1) {
      double ov = __shfl_xor(bv, off, 64);
      int oi = __shfl_xor(bi, off, 64);
      if (ov > bv || (ov == bv && oi < bi)) { bv = ov; bi = oi; }
    }

    bool cond = (bv <= 1e-8) && (bi > 0);
    if (!cond || iter == 511) break;   // fixed point (exact) or last body
    t = bi; p = (t - 1) >> 1;
    if (lane == 0) kfS[t] += 1.0f;
    __syncthreads();
    ++iter;
  }

#pragma unroll
  for (int u = 0; u < 8; ++u) {
    int n = lane + (u << 6);
    if (n < NNOD) a_node_out[n] = areg[u];
  }
}

// ---------------------------------------------------------------------------
// Kernel 4: out[b][n] = clip(qnodeT[n][b], 0, a_node[n]).
// Pure transpose-clip: qnodeT holds exactly the bits the old k_out walk
// produced, and the double clip ops are verbatim => identical output bits.
// ---------------------------------------------------------------------------
__global__ __launch_bounds__(256) void k_clip(const float* __restrict__ qnodeT,
                                              const double* __restrict__ a_node,
                                              float* __restrict__ out) {
  __shared__ float tile[64][65];
  __shared__ double anS[64];
  const int n0 = blockIdx.x * 64;
  const int b0 = blockIdx.y * 64;
  const int tid = threadIdx.x;
  if (tid < 64) anS[tid] = (n0 + tid < NNOD) ? a_node[n0 + tid] : 0.0;
  for (int i = tid; i < 64 * 64; i += 256) {
    int ni = i >> 6, bj = i & 63;
    int nn = n0 + ni;
    tile[ni][bj] = (nn < NNOD) ? qnodeT[nn * BATCH + b0 + bj] : 0.f;
  }
  __syncthreads();
  for (int i = tid; i < 64 * 64; i += 256) {
    int bi = i >> 6, nj = i & 63;
    int nn = n0 + nj;
    if (nn < NNOD) {
      float q = tile[nj][bi];
      double r = fmin(fmax((double)q, 0.0), anS[nj]);
      out[(size_t)(b0 + bi) * NNOD + nn] = (float)r;
    }
  }
}

// ---------------------------------------------------------------------------
extern "C" void kernel_launch(void* const* d_in, const int* in_sizes, int n_in,
                              void* d_out, int out_size, void* d_ws, size_t ws_size,
                              hipStream_t stream) {
  (void)in_sizes; (void)n_in; (void)out_size;
  const float* x    = (const float*)d_in[0];
  const float* W    = (const float*)d_in[1];
  const float* bias = (const float*)d_in[2];
  float* out = (float*)d_out;

  char* ws = (char*)d_ws;
  const size_t PART_STRIDE = 256 * BATCH * sizeof(float);   // 524288 B per chunk
  const size_t QS = 524288;    // qsT (255*512*4 = 522240, padded)
  const size_t QN = 1048576;   // qnodeT (511*512*4 = 1046528, padded)
  const size_t GA = 43008;     // ga (42924, padded)
  const size_t AG = 4096;      // agrp0 (4088, padded)
  const size_t AN = 4096;      // a_node (4088, padded)
  const size_t TAIL = QS + QN + GA + AG + AN;

  int n = 8;
  while (n > 1 && (size_t)n * PART_STRIDE + TAIL > ws_size) n >>= 1;
  bool splitk_ok = ((size_t)n * PART_STRIDE + TAIL <= ws_size);

  size_t P = splitk_ok ? (size_t)n * PART_STRIDE : 0;
  float*  qsT    = (float*) (ws + P);
  float*  qnodeT = (float*) (ws + P + QS);
  float*  ga     = (float*) (ws + P + QS + QN);
  double* agrp0  = (double*)(ws + P + QS + QN + GA);
  double* a_node = (double*)(ws + P + QS + QN + GA + AG);

  // One-time host-side occupancy check for the cooperative path (pure queries,
  // graph-capture-safe: no allocation, no sync, no stream ops).
  static int coop_state = -1;
  if (coop_state < 0) {
    int dev = 0, cu = 0, nb = 0;
    hipError_t e0 = hipGetDevice(&dev);
    hipError_t e1 = hipDeviceGetAttribute(&cu, hipDeviceAttributeMultiprocessorCount, dev);
    hipError_t e2 = hipOccupancyMaxActiveBlocksPerMultiprocessor(&nb, k_front, 256, 0);
    coop_state = (e0 == hipSuccess && e1 == hipSuccess && e2 == hipSuccess &&
                  (long)nb * (long)cu >= NNOD) ? 1 : 0;
  }

  bool front_done = false;
  if (splitk_ok && n == 8 && coop_state == 1) {
    float* partial = (float*)ws;
    void* args[] = {(void*)&x, (void*)&W, (void*)&bias, (void*)&partial,
                    (void*)&qsT, (void*)&ga, (void*)&agrp0, (void*)&qnodeT};
    hipError_t e = hipLaunchCooperativeKernel((const void*)k_front, dim3(NNOD),
                                              dim3(256), args, 0, stream);
    if (e == hipSuccess) front_done = true;
    else coop_state = 0;   // don't retry the coop path
  }

  if (!front_done) {
    if (splitk_ok) {
      float* partial = (float*)ws;
      k_qgemm<<<dim3(4, 8, n), dim3(256), 0, stream>>>(x, W, partial, 512 / n);
      k_qreduce<<<dim3(510), dim3(256), 0, stream>>>(partial, bias, qsT, n);
    } else {
      k_qsplitT_fb<<<dim3(64), dim3(256), 0, stream>>>(x, W, bias, qsT);
    }
    k_ga<<<dim3(NNOD), dim3(256), 0, stream>>>(qsT, ga, agrp0, qnodeT);
  }
  k_scan<<<dim3(1), dim3(64), 0, stream>>>(ga, agrp0, a_node);
  k_clip<<<dim3(8, 8), dim3(256), 0, stream>>>(qnodeT, a_node, out);
}

// Round 6
// 97.371 us; speedup vs baseline: 2.2985x; 2.2985x over previous
//
#include <hip/hip_runtime.h>
#include <hip/hip_bf16.h>
#include <math.h>

// Sizes fixed by the reference setup: B=512, F=512, max_depth=8 -> S=255 splits, N=511 nodes, NC=21.
#define BATCH 512
#define FDIM  512
#define NSPL  255
#define NNOD  511
#define NC    21

// NOTE (prior-session post-mortems): the scan's merge dynamics depend on EXACT
// bit-level ties. Changes that broke them (full 512-iter blowup, ~900 us):
//   (1) duplicating f64 blend expressions (ffp-contract divergence);
//   (2) replacing __shfl_xor butterflies with DPP/swizzle equivalents.
// The shfl butterflies and every FP expression below are byte-identical to the
// validated version.
//
// SESSION LEDGER:
//  R1: reduce fused into k_ga -> +6.4 us (57 MB redundant partial reads). Reverted.
//  R3: intra-grid ticket+__threadfence fixup -> CATASTROPHIC (gemm 3->68 us;
//      cross-XCD L2 writeback serialization).
//  R4: full-K GEMM, 128 blocks -> gemm ~23-31 us (no split-K register-blocking
//      economics). Reverted.
//  R5: cooperative grid.sync -> ~60 us PER SYNC on 511 blocks. Removed.
//  FIRM LESSON: no cheap inter-block coherence point on gfx950 except the
//  launch boundary. 5-launch split-K structure is the right shape.
//  R6 (this): k_scan micro-opt, value-preserving only: (a) drop in-loop
//  __syncthreads (single 64-lane wave; LDS is per-wave FIFO; compiler keeps
//  program-order ds_write->ds_read + lgkmcnt => identical bits); (b) phase-N
//  reads k from lane-local register mirror kreg[u] (n = lane+u*64 is
//  lane-owned; same float += 1.0f sequence => identical values); LDS kfS kept
//  for phase Z's cross-lane reads. No FP expression or shfl changed.

// ---------------------------------------------------------------------------
// Kernel 1: tiled split-K GEMM. partial[z][s][b] = sum_{f in chunk z} W[f,s]*x[b,f]
// (byte-identical to the validated version)
// ---------------------------------------------------------------------------
__global__ __launch_bounds__(256) void k_qgemm(const float* __restrict__ x,
                                               const float* __restrict__ W,
                                               float* __restrict__ partial,
                                               int fpc) {
  __shared__ float Ws[64 * 68];
  __shared__ float xT[64 * 68];
  const int tid = threadIdx.x;
  const int s0 = blockIdx.x * 64;
  const int b0 = blockIdx.y * 64;
  const int f0 = blockIdx.z * fpc;
  const int sx = tid & 15;
  const int by = tid >> 4;
  float acc[4][4];
#pragma unroll
  for (int i = 0; i < 4; ++i)
#pragma unroll
    for (int j = 0; j < 4; ++j) acc[i][j] = 0.f;

  for (int fc = f0; fc < f0 + fpc; fc += 64) {
    {
      int si = tid & 63, fr = tid >> 6;
#pragma unroll
      for (int r = 0; r < 16; ++r) {
        int fi = fr + r * 4;
        int s = s0 + si;
        Ws[fi * 68 + si] = (s < NSPL) ? W[(fc + fi) * NSPL + s] : 0.f;
      }
      int j = tid & 63, ir = tid >> 6;
#pragma unroll
      for (int r = 0; r < 16; ++r) {
        int i = ir + r * 4;
        xT[j * 68 + i] = x[(b0 + i) * FDIM + (fc + j)];
      }
    }
    __syncthreads();
#pragma unroll 8
    for (int f = 0; f < 64; ++f) {
      float4 av = *(const float4*)&Ws[f * 68 + sx * 4];
      float4 xv = *(const float4*)&xT[f * 68 + by * 4];
      const float a4[4] = {av.x, av.y, av.z, av.w};
      const float x4[4] = {xv.x, xv.y, xv.z, xv.w};
#pragma unroll
      for (int i = 0; i < 4; ++i)
#pragma unroll
        for (int j = 0; j < 4; ++j) acc[i][j] += a4[i] * x4[j];
    }
    __syncthreads();
  }

  float* pout = partial + (size_t)blockIdx.z * (256 * BATCH);
#pragma unroll
  for (int i = 0; i < 4; ++i) {
    int s = s0 + sx * 4 + i;
    if (s < NSPL) {
      float4 v = make_float4(acc[i][0], acc[i][1], acc[i][2], acc[i][3]);
      *(float4*)&pout[s * BATCH + b0 + by * 4] = v;
    }
  }
}

// Reduce: qsT[s][b] = (sum_z partial[z][s][b], ascending z) + bias[s]
__global__ __launch_bounds__(256) void k_qreduce(const float* __restrict__ partial,
                                                 const float* __restrict__ bias,
                                                 float* __restrict__ qsT, int n) {
  int idx = blockIdx.x * 256 + threadIdx.x;
  if (idx >= NSPL * BATCH) return;
  int s = idx >> 9;
  float v = 0.f;
  for (int c = 0; c < n; ++c) v += partial[(size_t)c * (256 * BATCH) + idx];
  qsT[idx] = v + bias[s];
}

// Fallback GEMM (used only if workspace too small for split-K).
__global__ __launch_bounds__(256) void k_qsplitT_fb(const float* __restrict__ x,
                                                    const float* __restrict__ W,
                                                    const float* __restrict__ bias,
                                                    float* __restrict__ qsT) {
  const int s = threadIdx.x;
  const int b0 = blockIdx.x * 8;
  if (s >= NSPL) return;
  float acc0[8], acc1[8];
#pragma unroll
  for (int i = 0; i < 8; ++i) { acc0[i] = 0.f; acc1[i] = 0.f; }
#pragma unroll 2
  for (int f = 0; f < 256; ++f) {
    float w0 = W[f * NSPL + s];
    float w1 = W[(f + 256) * NSPL + s];
#pragma unroll
    for (int i = 0; i < 8; ++i) {
      acc0[i] += x[(b0 + i) * FDIM + f] * w0;
      acc1[i] += x[(b0 + i) * FDIM + f + 256] * w1;
    }
  }
  float bs = bias[s];
#pragma unroll
  for (int i = 0; i < 8; ++i) qsT[s * BATCH + b0 + i] = (acc0[i] + acc1[i]) + bs;
}

// ---------------------------------------------------------------------------
// q_node walk (validated — same fminf chain as the original reference path)
// ---------------------------------------------------------------------------
__device__ __forceinline__ float qnode_walk(const float* __restrict__ qsT, int n, int b) {
  float q = 1.0f;
  int a = n;
  while (a > 0) {
    int p = (a - 1) >> 1;
    float v = qsT[p * BATCH + b];
    q = fminf(q, (a & 1) ? -v : v);
    a = p;
  }
  return q;
}

// ---------------------------------------------------------------------------
// Kernel 2 (fused): g_a row for node n (byte-identical arithmetic to the
// validated k_ga) + agrp0[n] + qnodeT[n][b] = q_node (free coalesced store,
// consumed by k_clip so it needn't re-walk the tree).
// ---------------------------------------------------------------------------
__global__ __launch_bounds__(256) void k_ga(const float* __restrict__ qsT,
                                            float* __restrict__ ga,
                                            double* __restrict__ agrp0,
                                            float* __restrict__ qnodeT) {
  const int n = blockIdx.x;
  const int tid = threadIdx.x;
  __shared__ float qs[BATCH];
  __shared__ double part[4][NC];
  __shared__ float gaRow[NC];
  __shared__ double zS[NC];
  __shared__ double eS[NC];
  __shared__ double mS;
#pragma unroll
  for (int rep = 0; rep < 2; ++rep) {
    int b = tid + rep * 256;
    float q = qnode_walk(qsT, n, b);
    qs[b] = q;
    qnodeT[n * BATCH + b] = q;
  }
  __syncthreads();
  if (tid < 4 * NC) {
    int c = tid % NC, chunk = tid / NC;
    double ac = 0.05 * (double)c;
    double ssum = 0.0;
    int b0 = chunk * 128;
    for (int b = b0; b < b0 + 128; ++b) {
      float qh = qs[b] + 0.5f;          // f32 add (NumPy scalar promotion keeps f32)
      double dqh = (double)qh;
      if (ac <= dqh) { double d = ac - dqh; ssum += d * d; }
    }
    part[chunk][c] = ssum;
  }
  __syncthreads();
  if (tid < NC) {
    double ac = 0.05 * (double)tid;
    double ssum = ((part[0][tid] + part[1][tid]) + part[2][tid]) + part[3][tid];
    float gv = (float)(0.5 * ac * ac + 0.5 * ssum);
    ga[n * NC + tid] = gv;
    gaRow[tid] = gv;    // same f32 bits the serial softmin consumed
  }
  __syncthreads();

  // --- softmin: exps parallel across 21 lanes (deterministic => same bits);
  //     order-sensitive chains (m, S, A) verbatim serial on tid 0 ---
  if (tid < NC) zS[tid] = -100.0 * (double)gaRow[tid];
  __syncthreads();
  if (tid == 0) {
    double m = -1e300;
#pragma unroll
    for (int c = 0; c < NC; ++c) m = fmax(m, zS[c]);
    mS = m;
  }
  __syncthreads();
  if (tid < NC) eS[tid] = exp(zS[tid] - mS);
  __syncthreads();
  if (tid == 0) {
    double S = 0.0;
#pragma unroll
    for (int c = 0; c < NC; ++c) S += eS[c];
    double A = 0.0;
#pragma unroll
    for (int c = 0; c < NC; ++c) A += (0.05 * (double)c) * (eS[c] / S);
    agrp0[n] = A;
  }
}

// ---------------------------------------------------------------------------
// Kernel 3: the sequential scan. All FP expressions and __shfl_xor butterflies
// are byte-identical to the validated version. R6 changes are value-preserving
// only: in-loop __syncthreads removed (single 64-lane wave; per-wave LDS FIFO
// + compiler-ordered ds_write->ds_read guarantee identical observed bits), and
// phase N reads k from a lane-local register mirror (n = lane+u*64 is owned by
// exactly this lane; same float += 1.0f update sequence => identical values).
// kfS in LDS is retained for phase Z's cross-lane reads.
// ---------------------------------------------------------------------------
__global__ __launch_bounds__(64) void k_scan(const float* __restrict__ ga_g,
                                             const double* __restrict__ agrp0,
                                             double* __restrict__ a_node_out) {
  __shared__ float gaS[NNOD * NC];        // 42924 B
  __shared__ double agrp[512];            // 4096 B
  __shared__ double anode[512];           // 4096 B
  __shared__ float kfS[512];              // 2048 B
  const int lane = threadIdx.x;

  {
    const float4* src = (const float4*)ga_g;
    float4* dst = (float4*)gaS;
    const int n4 = (NNOD * NC) / 4;       // 2682
#pragma unroll 4
    for (int i = lane; i < n4; i += 64) dst[i] = src[i];
    if (lane < (NNOD * NC) - n4 * 4) gaS[n4 * 4 + lane] = ga_g[n4 * 4 + lane];
  }
  for (int i = lane; i < 512; i += 64) {
    agrp[i] = (i < NNOD) ? agrp0[i] : 0.0;
    anode[i] = 0.0;
    kfS[i] = 0.0f;
  }
  float kreg[8];                          // lane-local mirror of kfS[lane + u*64]
#pragma unroll
  for (int u = 0; u < 8; ++u) kreg[u] = 0.0f;
  __syncthreads();

  int t = 0, p = 0;
  double areg[8];
  int iter = 0;
  for (;;) {
    if (iter > 0) {
      // phase Z: recompute a_grp for groups t (lanes 0..31) and p (lanes 32..63)
      int j = lane >> 5, c = lane & 31;
      int g = j ? p : t;
      double z = -1e300;
      if (c < NC) {
        double acc = (1.0 - (double)kfS[g]) * (double)gaS[g * NC + c];
        int l = 2 * g + 1, r = 2 * g + 2;
        if (l < NNOD) acc = acc + (double)kfS[l] * (double)gaS[l * NC + c];
        if (r < NNOD) acc = acc + (double)kfS[r] * (double)gaS[r * NC + c];
        z = -100.0 * acc;
      }
      double m = z;
#pragma unroll
      for (int off = 16; off >= 1; off >>= 1) m = fmax(m, __shfl_xor(m, off, 32));
      double e = (c < NC) ? exp(z - m) : 0.0;
      double S = e;
#pragma unroll
      for (int off = 16; off >= 1; off >>= 1) S += __shfl_xor(S, off, 32);
      double term = (c < NC) ? (0.05 * (double)c) * (e / S) : 0.0;
#pragma unroll
      for (int off = 16; off >= 1; off >>= 1) term += __shfl_xor(term, off, 32);
      if (c == 0) agrp[g] = term;
      // (no barrier: single wave, per-wave LDS FIFO orders write->read)
    }

    // phase N: a_node[n] = k_n*a_grp[par] + (1-k_n)*a_grp[n]
#pragma unroll
    for (int u = 0; u < 8; ++u) {
      int n = lane + (u << 6);
      if (n < NNOD) {
        double kn = (double)kreg[u];      // lane-local mirror, identical value to kfS[n]
        double agn = agrp[n];
        double an;
        if (n == 0) an = agn;
        else an = kn * agrp[(n - 1) >> 1] + (1.0 - kn) * agn;
        areg[u] = an;
        anode[n] = an;
      }
    }
    // (no barrier)

    // phase V: viol + argmax (first-index tie-break)
    double bv = -1e300; int bi = 0x7fffffff;
#pragma unroll
    for (int u = 0; u < 8; ++u) {
      int n = lane + (u << 6);
      if (n < NNOD) {
        double ap = (n == 0) ? 1.0 : anode[(n - 1) >> 1];
        double vi = areg[u] - ap;
        if (vi > bv) { bv = vi; bi = n; }
      }
    }
#pragma unroll
    for (int off = 32; off >= 1; off >>= 1) {
      double ov = __shfl_xor(bv, off, 64);
      int oi = __shfl_xor(bi, off, 64);
      if (ov > bv || (ov == bv && oi < bi)) { bv = ov; bi = oi; }
    }

    bool cond = (bv <= 1e-8) && (bi > 0);
    if (!cond || iter == 511) break;   // fixed point (exact) or last body
    t = bi; p = (t - 1) >> 1;
    if (lane == 0) kfS[t] += 1.0f;     // LDS copy (phase Z cross-lane reads)
#pragma unroll
    for (int u = 0; u < 8; ++u)        // register mirror: same += 1.0f on owner lane
      if (u == (t >> 6) && lane == (t & 63)) kreg[u] += 1.0f;
    // (no barrier)
    ++iter;
  }

#pragma unroll
  for (int u = 0; u < 8; ++u) {
    int n = lane + (u << 6);
    if (n < NNOD) a_node_out[n] = areg[u];
  }
}

// ---------------------------------------------------------------------------
// Kernel 4: out[b][n] = clip(qnodeT[n][b], 0, a_node[n]).
// Pure transpose-clip: qnodeT holds exactly the bits the old k_out walk
// produced, and the double clip ops are verbatim => identical output bits.
// ---------------------------------------------------------------------------
__global__ __launch_bounds__(256) void k_clip(const float* __restrict__ qnodeT,
                                              const double* __restrict__ a_node,
                                              float* __restrict__ out) {
  __shared__ float tile[64][65];
  __shared__ double anS[64];
  const int n0 = blockIdx.x * 64;
  const int b0 = blockIdx.y * 64;
  const int tid = threadIdx.x;
  if (tid < 64) anS[tid] = (n0 + tid < NNOD) ? a_node[n0 + tid] : 0.0;
  for (int i = tid; i < 64 * 64; i += 256) {
    int ni = i >> 6, bj = i & 63;
    int nn = n0 + ni;
    tile[ni][bj] = (nn < NNOD) ? qnodeT[nn * BATCH + b0 + bj] : 0.f;
  }
  __syncthreads();
  for (int i = tid; i < 64 * 64; i += 256) {
    int bi = i >> 6, nj = i & 63;
    int nn = n0 + nj;
    if (nn < NNOD) {
      float q = tile[nj][bi];
      double r = fmin(fmax((double)q, 0.0), anS[nj]);
      out[(size_t)(b0 + bi) * NNOD + nn] = (float)r;
    }
  }
}

// ---------------------------------------------------------------------------
extern "C" void kernel_launch(void* const* d_in, const int* in_sizes, int n_in,
                              void* d_out, int out_size, void* d_ws, size_t ws_size,
                              hipStream_t stream) {
  (void)in_sizes; (void)n_in; (void)out_size;
  const float* x    = (const float*)d_in[0];
  const float* W    = (const float*)d_in[1];
  const float* bias = (const float*)d_in[2];
  float* out = (float*)d_out;

  char* ws = (char*)d_ws;
  const size_t PART_STRIDE = 256 * BATCH * sizeof(float);   // 524288 B per chunk
  const size_t QS = 524288;    // qsT (255*512*4 = 522240, padded)
  const size_t QN = 1048576;   // qnodeT (511*512*4 = 1046528, padded)
  const size_t GA = 43008;     // ga (42924, padded)
  const size_t AG = 4096;      // agrp0 (4088, padded)
  const size_t AN = 4096;      // a_node (4088, padded)
  const size_t TAIL = QS + QN + GA + AG + AN;

  int n = 8;
  while (n > 1 && (size_t)n * PART_STRIDE + TAIL > ws_size) n >>= 1;
  bool splitk_ok = ((size_t)n * PART_STRIDE + TAIL <= ws_size);

  size_t P = splitk_ok ? (size_t)n * PART_STRIDE : 0;
  float*  qsT    = (float*) (ws + P);
  float*  qnodeT = (float*) (ws + P + QS);
  float*  ga     = (float*) (ws + P + QS + QN);
  double* agrp0  = (double*)(ws + P + QS + QN + GA);
  double* a_node = (double*)(ws + P + QS + QN + GA + AG);

  if (splitk_ok) {
    float* partial = (float*)ws;
    k_qgemm<<<dim3(4, 8, n), dim3(256), 0, stream>>>(x, W, partial, 512 / n);
    k_qreduce<<<dim3(510), dim3(256), 0, stream>>>(partial, bias, qsT, n);
  } else {
    k_qsplitT_fb<<<dim3(64), dim3(256), 0, stream>>>(x, W, bias, qsT);
  }
  k_ga<<<dim3(NNOD), dim3(256), 0, stream>>>(qsT, ga, agrp0, qnodeT);
  k_scan<<<dim3(1), dim3(64), 0, stream>>>(ga, agrp0, a_node);
  k_clip<<<dim3(8, 8), dim3(256), 0, stream>>>(qnodeT, a_node, out);
}

// Round 7
// 93.561 us; speedup vs baseline: 2.3921x; 1.0407x over previous
//
#include <hip/hip_runtime.h>
#include <hip/hip_bf16.h>
#include <math.h>

// Sizes fixed by the reference setup: B=512, F=512, max_depth=8 -> S=255 splits, N=511 nodes, NC=21.
#define BATCH 512
#define FDIM  512
#define NSPL  255
#define NNOD  511
#define NC    21

// SESSION LEDGER (7 benches, all absmax-bit-exact 0.0002441406):
//  R0 (this config): 94.0 us (92.9 prior session) — BEST MEASURED.
//  R1: reduce fused into k_ga -> 100.4 (57 MB redundant partial re-reads).
//  R2: qnodeT+k_clip + parallel-exp tail -> 96.3 (neutral-to-slightly-worse).
//  R3: intra-grid ticket+__threadfence fixup -> 150.6 (gemm 3->68 us;
//      cross-XCD L2 coherence serialization. NEVER fence across blocks).
//  R4: full-K GEMM -> 113.1 (loses split-K register-blocking economics).
//  R5: cooperative grid.sync -> 223.8 (~60 us PER SYNC on 511 blocks).
//  R6: scan w/o in-loop barriers + kreg mirror -> 97.4 (NEUTRAL: single-wave
//      s_barrier is free; scan cost is the shfl/exp dependency chain).
// ACCOUNTING (Model B, fits all 7): dur ~= harness ws-fill (~40 us, 268 MB
// @6.6 TB/s, untouchable) + ~2.5 us/launch + scan ~30-36 us (frozen, see
// below) + ~8 us real kernel work. Floor ~= 91 us. This config measures
// 92.9-94.0. All structural levers beyond it are measured-blocked.
//
// NOTE (prior-session post-mortems): the scan's merge dynamics depend on EXACT
// bit-level ties. Two classes of change have empirically broken them (full
// 512-iteration blowup, ~900 us):
//   (1) duplicating f64 blend expressions (ffp-contract divergence);
//   (2) replacing __shfl_xor butterflies with DPP/swizzle equivalents
//       (mechanism unidentified — DO NOT retry without offline bit-diffing).
// k_scan below is byte-identical to the validated version.

// ---------------------------------------------------------------------------
// Kernel 1: tiled split-K GEMM. partial[z][s][b] = sum_{f in chunk z} W[f,s]*x[b,f]
// ---------------------------------------------------------------------------
__global__ __launch_bounds__(256) void k_qgemm(const float* __restrict__ x,
                                               const float* __restrict__ W,
                                               float* __restrict__ partial,
                                               int fpc) {
  __shared__ float Ws[64 * 68];
  __shared__ float xT[64 * 68];
  const int tid = threadIdx.x;
  const int s0 = blockIdx.x * 64;
  const int b0 = blockIdx.y * 64;
  const int f0 = blockIdx.z * fpc;
  const int sx = tid & 15;
  const int by = tid >> 4;
  float acc[4][4];
#pragma unroll
  for (int i = 0; i < 4; ++i)
#pragma unroll
    for (int j = 0; j < 4; ++j) acc[i][j] = 0.f;

  for (int fc = f0; fc < f0 + fpc; fc += 64) {
    {
      int si = tid & 63, fr = tid >> 6;
#pragma unroll
      for (int r = 0; r < 16; ++r) {
        int fi = fr + r * 4;
        int s = s0 + si;
        Ws[fi * 68 + si] = (s < NSPL) ? W[(fc + fi) * NSPL + s] : 0.f;
      }
      int j = tid & 63, ir = tid >> 6;
#pragma unroll
      for (int r = 0; r < 16; ++r) {
        int i = ir + r * 4;
        xT[j * 68 + i] = x[(b0 + i) * FDIM + (fc + j)];
      }
    }
    __syncthreads();
#pragma unroll 8
    for (int f = 0; f < 64; ++f) {
      float4 av = *(const float4*)&Ws[f * 68 + sx * 4];
      float4 xv = *(const float4*)&xT[f * 68 + by * 4];
      const float a4[4] = {av.x, av.y, av.z, av.w};
      const float x4[4] = {xv.x, xv.y, xv.z, xv.w};
#pragma unroll
      for (int i = 0; i < 4; ++i)
#pragma unroll
        for (int j = 0; j < 4; ++j) acc[i][j] += a4[i] * x4[j];
    }
    __syncthreads();
  }

  float* pout = partial + (size_t)blockIdx.z * (256 * BATCH);
#pragma unroll
  for (int i = 0; i < 4; ++i) {
    int s = s0 + sx * 4 + i;
    if (s < NSPL) {
      float4 v = make_float4(acc[i][0], acc[i][1], acc[i][2], acc[i][3]);
      *(float4*)&pout[s * BATCH + b0 + by * 4] = v;
    }
  }
}

// Reduce: qsT[s][b] = (sum_z partial[z][s][b], ascending z) + bias[s]
__global__ __launch_bounds__(256) void k_qreduce(const float* __restrict__ partial,
                                                 const float* __restrict__ bias,
                                                 float* __restrict__ qsT, int n) {
  int idx = blockIdx.x * 256 + threadIdx.x;
  if (idx >= NSPL * BATCH) return;
  int s = idx >> 9;
  float v = 0.f;
  for (int c = 0; c < n; ++c) v += partial[(size_t)c * (256 * BATCH) + idx];
  qsT[idx] = v + bias[s];
}

// Fallback GEMM (used only if workspace too small for split-K).
__global__ __launch_bounds__(256) void k_qsplitT_fb(const float* __restrict__ x,
                                                    const float* __restrict__ W,
                                                    const float* __restrict__ bias,
                                                    float* __restrict__ qsT) {
  const int s = threadIdx.x;
  const int b0 = blockIdx.x * 8;
  if (s >= NSPL) return;
  float acc0[8], acc1[8];
#pragma unroll
  for (int i = 0; i < 8; ++i) { acc0[i] = 0.f; acc1[i] = 0.f; }
#pragma unroll 2
  for (int f = 0; f < 256; ++f) {
    float w0 = W[f * NSPL + s];
    float w1 = W[(f + 256) * NSPL + s];
#pragma unroll
    for (int i = 0; i < 8; ++i) {
      acc0[i] += x[(b0 + i) * FDIM + f] * w0;
      acc1[i] += x[(b0 + i) * FDIM + f + 256] * w1;
    }
  }
  float bs = bias[s];
#pragma unroll
  for (int i = 0; i < 8; ++i) qsT[s * BATCH + b0 + i] = (acc0[i] + acc1[i]) + bs;
}

// ---------------------------------------------------------------------------
// q_node walk (shared by kernels 2 and 4 so bit patterns match)
// ---------------------------------------------------------------------------
__device__ __forceinline__ float qnode_walk(const float* __restrict__ qsT, int n, int b) {
  float q = 1.0f;
  int a = n;
  while (a > 0) {
    int p = (a - 1) >> 1;
    float v = qsT[p * BATCH + b];
    q = fminf(q, (a & 1) ? -v : v);
    a = p;
  }
  return q;
}

// ---------------------------------------------------------------------------
// Kernel 2 (fused): g_a row for node n (byte-identical arithmetic to the
// validated k_ga) + agrp0[n] via the byte-identical serial loop from the
// validated k_agrp0, run by thread 0 on the SAME stored f32 row values.
// ---------------------------------------------------------------------------
__global__ __launch_bounds__(256) void k_ga(const float* __restrict__ qsT,
                                            float* __restrict__ ga,
                                            double* __restrict__ agrp0) {
  const int n = blockIdx.x;
  const int tid = threadIdx.x;
  __shared__ float qs[BATCH];
  __shared__ double part[4][NC];
  __shared__ float gaRow[NC];
#pragma unroll
  for (int rep = 0; rep < 2; ++rep) {
    int b = tid + rep * 256;
    qs[b] = qnode_walk(qsT, n, b);
  }
  __syncthreads();
  if (tid < 4 * NC) {
    int c = tid % NC, chunk = tid / NC;
    double ac = 0.05 * (double)c;
    double ssum = 0.0;
    int b0 = chunk * 128;
    for (int b = b0; b < b0 + 128; ++b) {
      float qh = qs[b] + 0.5f;          // f32 add (NumPy scalar promotion keeps f32)
      double dqh = (double)qh;
      if (ac <= dqh) { double d = ac - dqh; ssum += d * d; }
    }
    part[chunk][c] = ssum;
  }
  __syncthreads();
  if (tid < NC) {
    double ac = 0.05 * (double)tid;
    double ssum = ((part[0][tid] + part[1][tid]) + part[2][tid]) + part[3][tid];
    float gv = (float)(0.5 * ac * ac + 0.5 * ssum);
    ga[n * NC + tid] = gv;
    gaRow[tid] = gv;    // same f32 bits k_agrp0 would have re-read from global
  }
  __syncthreads();
  if (tid == 0) {
    // byte-identical serial softmin from the validated k_agrp0
    double z[NC], m = -1e300;
#pragma unroll
    for (int c = 0; c < NC; ++c) { z[c] = -100.0 * (double)gaRow[c]; m = fmax(m, z[c]); }
    double S = 0.0;
#pragma unroll
    for (int c = 0; c < NC; ++c) { z[c] = exp(z[c] - m); S += z[c]; }
    double A = 0.0;
#pragma unroll
    for (int c = 0; c < NC; ++c) A += (0.05 * (double)c) * (z[c] / S);
    agrp0[n] = A;
  }
}

// ---------------------------------------------------------------------------
// Kernel 3: the sequential scan — BYTE-IDENTICAL to the validated round-2/4
// version. anode array is load-bearing (exact-tie mechanism); __shfl_xor
// butterflies are load-bearing (see note at top). Do not touch.
// ---------------------------------------------------------------------------
__global__ __launch_bounds__(64) void k_scan(const float* __restrict__ ga_g,
                                             const double* __restrict__ agrp0,
                                             double* __restrict__ a_node_out) {
  __shared__ float gaS[NNOD * NC];        // 42924 B
  __shared__ double agrp[512];            // 4096 B
  __shared__ double anode[512];           // 4096 B
  __shared__ float kfS[512];              // 2048 B
  const int lane = threadIdx.x;

  {
    const float4* src = (const float4*)ga_g;
    float4* dst = (float4*)gaS;
    const int n4 = (NNOD * NC) / 4;       // 2682
#pragma unroll 4
    for (int i = lane; i < n4; i += 64) dst[i] = src[i];
    if (lane < (NNOD * NC) - n4 * 4) gaS[n4 * 4 + lane] = ga_g[n4 * 4 + lane];
  }
  for (int i = lane; i < 512; i += 64) {
    agrp[i] = (i < NNOD) ? agrp0[i] : 0.0;
    anode[i] = 0.0;
    kfS[i] = 0.0f;
  }
  __syncthreads();

  int t = 0, p = 0;
  double areg[8];
  int iter = 0;
  for (;;) {
    if (iter > 0) {
      // phase Z: recompute a_grp for groups t (lanes 0..31) and p (lanes 32..63)
      int j = lane >> 5, c = lane & 31;
      int g = j ? p : t;
      double z = -1e300;
      if (c < NC) {
        double acc = (1.0 - (double)kfS[g]) * (double)gaS[g * NC + c];
        int l = 2 * g + 1, r = 2 * g + 2;
        if (l < NNOD) acc = acc + (double)kfS[l] * (double)gaS[l * NC + c];
        if (r < NNOD) acc = acc + (double)kfS[r] * (double)gaS[r * NC + c];
        z = -100.0 * acc;
      }
      double m = z;
#pragma unroll
      for (int off = 16; off >= 1; off >>= 1) m = fmax(m, __shfl_xor(m, off, 32));
      double e = (c < NC) ? exp(z - m) : 0.0;
      double S = e;
#pragma unroll
      for (int off = 16; off >= 1; off >>= 1) S += __shfl_xor(S, off, 32);
      double term = (c < NC) ? (0.05 * (double)c) * (e / S) : 0.0;
#pragma unroll
      for (int off = 16; off >= 1; off >>= 1) term += __shfl_xor(term, off, 32);
      if (c == 0) agrp[g] = term;
      __syncthreads();
    }

    // phase N: a_node[n] = k_n*a_grp[par] + (1-k_n)*a_grp[n]
#pragma unroll
    for (int u = 0; u < 8; ++u) {
      int n = lane + (u << 6);
      if (n < NNOD) {
        double kn = (double)kfS[n];
        double agn = agrp[n];
        double an;
        if (n == 0) an = agn;
        else an = kn * agrp[(n - 1) >> 1] + (1.0 - kn) * agn;
        areg[u] = an;
        anode[n] = an;
      }
    }
    __syncthreads();

    // phase V: viol + argmax (first-index tie-break)
    double bv = -1e300; int bi = 0x7fffffff;
#pragma unroll
    for (int u = 0; u < 8; ++u) {
      int n = lane + (u << 6);
      if (n < NNOD) {
        double ap = (n == 0) ? 1.0 : anode[(n - 1) >> 1];
        double vi = areg[u] - ap;
        if (vi > bv) { bv = vi; bi = n; }
      }
    }
#pragma unroll
    for (int off = 32; off >= 1; off >>= 1) {
      double ov = __shfl_xor(bv, off, 64);
      int oi = __shfl_xor(bi, off, 64);
      if (ov > bv || (ov == bv && oi < bi)) { bv = ov; bi = oi; }
    }

    bool cond = (bv <= 1e-8) && (bi > 0);
    if (!cond || iter == 511) break;   // fixed point (exact) or last body
    t = bi; p = (t - 1) >> 1;
    if (lane == 0) kfS[t] += 1.0f;
    __syncthreads();
    ++iter;
  }

#pragma unroll
  for (int u = 0; u < 8; ++u) {
    int n = lane + (u << 6);
    if (n < NNOD) a_node_out[n] = areg[u];
  }
}

// ---------------------------------------------------------------------------
// Kernel 4: out[b][n] = clip(q_node[b,n], 0, a_node[n]).
// One block per b; qsT column staged in LDS (same f32 values, same fminf
// chain => same bits; and k_out is downstream of all decisions anyway).
// ---------------------------------------------------------------------------
__global__ __launch_bounds__(256) void k_out(const float* __restrict__ qsT,
                                             const double* __restrict__ a_node,
                                             float* __restrict__ out) {
  __shared__ float col[NSPL];
  const int b = blockIdx.x;
  const int tid = threadIdx.x;
  if (tid < NSPL) col[tid] = qsT[tid * BATCH + b];
  __syncthreads();
#pragma unroll
  for (int rep = 0; rep < 2; ++rep) {
    int n = tid + rep * 256;
    if (n < NNOD) {
      float q = 1.0f;
      int a = n;
      while (a > 0) {
        int p = (a - 1) >> 1;
        float v = col[p];
        q = fminf(q, (a & 1) ? -v : v);
        a = p;
      }
      double r = fmin(fmax((double)q, 0.0), a_node[n]);
      out[(size_t)b * NNOD + n] = (float)r;
    }
  }
}

// ---------------------------------------------------------------------------
extern "C" void kernel_launch(void* const* d_in, const int* in_sizes, int n_in,
                              void* d_out, int out_size, void* d_ws, size_t ws_size,
                              hipStream_t stream) {
  (void)in_sizes; (void)n_in; (void)out_size;
  const float* x    = (const float*)d_in[0];
  const float* W    = (const float*)d_in[1];
  const float* bias = (const float*)d_in[2];
  float* out = (float*)d_out;

  char* ws = (char*)d_ws;
  const size_t PART_STRIDE = 256 * BATCH * sizeof(float);   // 524288 B per chunk
  const size_t TAIL = 575488;                                // qsT+ga+agrp0+a_node (padded)

  int n = 8;
  while (n > 1 && (size_t)n * PART_STRIDE + TAIL > ws_size) n >>= 1;
  bool splitk_ok = ((size_t)n * PART_STRIDE + TAIL <= ws_size);

  size_t P = splitk_ok ? (size_t)n * PART_STRIDE : 0;
  float*  qsT    = (float*) (ws + P);
  float*  ga     = (float*) (ws + P + 524288);
  double* agrp0  = (double*)(ws + P + 567296);
  double* a_node = (double*)(ws + P + 571392);

  if (splitk_ok) {
    float* partial = (float*)ws;
    k_qgemm<<<dim3(4, 8, n), dim3(256), 0, stream>>>(x, W, partial, 512 / n);
    k_qreduce<<<dim3(510), dim3(256), 0, stream>>>(partial, bias, qsT, n);
  } else {
    k_qsplitT_fb<<<dim3(64), dim3(256), 0, stream>>>(x, W, bias, qsT);
  }
  k_ga<<<dim3(NNOD), dim3(256), 0, stream>>>(qsT, ga, agrp0);
  k_scan<<<dim3(1), dim3(64), 0, stream>>>(ga, agrp0, a_node);
  k_out<<<dim3(BATCH), dim3(256), 0, stream>>>(qsT, a_node, out);
}